// Round 2
// baseline (151.428 us; speedup 1.0000x reference)
//
#include <hip/hip_runtime.h>

// EuclideanLoss: loss = (1/(B*N)) * sum_{b,n} w_n * sqrt(sum_d (x[b,n,d]-y[b,d,n])^2)
// w_n = 1.5 for n in {1,2}. B=32, N=8192, D=64, fp32. 128 MiB moved, zero reuse.
//
// R7 == R6 resubmit: the R6 bench died with "MI355X container failed twice"
// (infra error — no compile/correctness signal). Kernel audit found no fault
// path: aligned float4 loads, 1024-block grid, no atomics, graph-capture safe.
//
// R6 rationale (from R5 evidence): duration tracked block count; 32KB-LDS
// staging capped occupancy at 5 blocks/CU and serialized on an 80-instruction
// global_load_lds stream + vmcnt(0) drain. This op has NO data reuse: LDS
// staging is pure overhead. Direct-to-register streaming instead:
//   wave ds (0..3) owns d-segment [16ds, 16ds+16); lane g owns n = n0+4g..+3.
//   y: float4 per (d, 4n) -> 1KB coalesced per wave instruction.
//   x: row-per-lane float4 (scattered per instr, 100% line utilization; L1
//      sector traffic 512KB/CU ~ 3.4us << 21us HBM floor).
// Cross-wave d-combine via a single 4KB LDS float4 exchange, then sqrt+weight,
// wave-reduce, per-block partial store (atomic-free, as R5 proved necessary).

constexpr int B  = 32;
constexpr int N  = 8192;
constexpr int D  = 64;
constexpr int TN = 256;               // n per block
constexpr int NBLK = (N / TN) * B;    // 1024 partials

__global__ __launch_bounds__(256) void euclid_loss_kernel(
    const float* __restrict__ x,   // [B, N, D]
    const float* __restrict__ y,   // [B, D, N]
    float* __restrict__ ws)        // [NBLK] per-block partials
{
    const int tid = threadIdx.x;
    const int ds  = tid >> 6;          // wave id = d-segment (0..3)
    const int g   = tid & 63;          // lane = n-group
    const int n0  = blockIdx.x * TN;
    const int b   = blockIdx.y;
    const int ng  = n0 + 4 * g;        // first of this thread's 4 n's
    const int d0  = ds * 16;           // first of this thread's 16 d's

    const float* xp = x + ((size_t)b * N + ng) * D + d0;  // 4 rows, stride D
    const float* yp = y + ((size_t)b * D + d0) * N + ng;  // 16 rows, stride N

    float acc0 = 0.f, acc1 = 0.f, acc2 = 0.f, acc3 = 0.f;

#pragma unroll
    for (int j = 0; j < 4; ++j) {
        const int dd = 4 * j;
        // y: 4 d-rows, each a coalesced float4 over this thread's 4 n's
        const float4 y0 = *reinterpret_cast<const float4*>(yp + (size_t)(dd + 0) * N);
        const float4 y1 = *reinterpret_cast<const float4*>(yp + (size_t)(dd + 1) * N);
        const float4 y2 = *reinterpret_cast<const float4*>(yp + (size_t)(dd + 2) * N);
        const float4 y3 = *reinterpret_cast<const float4*>(yp + (size_t)(dd + 3) * N);
        // x: 4 n-rows, each a float4 over d = d0+dd .. +3
        const float4 x0 = *reinterpret_cast<const float4*>(xp + 0 * D + dd);
        const float4 x1 = *reinterpret_cast<const float4*>(xp + 1 * D + dd);
        const float4 x2 = *reinterpret_cast<const float4*>(xp + 2 * D + dd);
        const float4 x3 = *reinterpret_cast<const float4*>(xp + 3 * D + dd);

        float d;
        d = x0.x - y0.x; acc0 += d * d;  d = x0.y - y1.x; acc0 += d * d;
        d = x0.z - y2.x; acc0 += d * d;  d = x0.w - y3.x; acc0 += d * d;
        d = x1.x - y0.y; acc1 += d * d;  d = x1.y - y1.y; acc1 += d * d;
        d = x1.z - y2.y; acc1 += d * d;  d = x1.w - y3.y; acc1 += d * d;
        d = x2.x - y0.z; acc2 += d * d;  d = x2.y - y1.z; acc2 += d * d;
        d = x2.z - y2.z; acc2 += d * d;  d = x2.w - y3.z; acc2 += d * d;
        d = x3.x - y0.w; acc3 += d * d;  d = x3.y - y1.w; acc3 += d * d;
        d = x3.z - y2.w; acc3 += d * d;  d = x3.w - y3.w; acc3 += d * d;
    }

    // Cross-wave combine of the 4 d-segments: 4 KB LDS, float4 (b128) traffic.
    __shared__ float4 part[4][64];     // [ds][g]
    part[ds][g] = make_float4(acc0, acc1, acc2, acc3);
    __syncthreads();

    if (ds == 0) {
        const float4 p0 = part[0][g];
        const float4 p1 = part[1][g];
        const float4 p2 = part[2][g];
        const float4 p3 = part[3][g];
        float v = 0.f;
        {
            const float s = p0.x + p1.x + p2.x + p3.x;
            const int   n = ng + 0;
            v += ((n == 1 || n == 2) ? 1.5f : 1.0f) * __builtin_sqrtf(s);
        }
        {
            const float s = p0.y + p1.y + p2.y + p3.y;
            const int   n = ng + 1;
            v += ((n == 1 || n == 2) ? 1.5f : 1.0f) * __builtin_sqrtf(s);
        }
        {
            const float s = p0.z + p1.z + p2.z + p3.z;
            const int   n = ng + 2;
            v += ((n == 1 || n == 2) ? 1.5f : 1.0f) * __builtin_sqrtf(s);
        }
        {
            const float s = p0.w + p1.w + p2.w + p3.w;
            const int   n = ng + 3;
            v += ((n == 1 || n == 2) ? 1.5f : 1.0f) * __builtin_sqrtf(s);
        }
#pragma unroll
        for (int off = 32; off > 0; off >>= 1) v += __shfl_down(v, off, 64);
        if (g == 0)
            ws[blockIdx.y * gridDim.x + blockIdx.x] = v;   // plain store, no atomic
    }
}

__global__ __launch_bounds__(256) void reduce_kernel(
    const float* __restrict__ ws,  // [NBLK] = 1024
    float* __restrict__ out)       // [1]
{
    const int tid = threadIdx.x;
    const float4 p = *reinterpret_cast<const float4*>(ws + tid * 4);
    float v = p.x + p.y + p.z + p.w;
#pragma unroll
    for (int off = 32; off > 0; off >>= 1) v += __shfl_down(v, off, 64);

    __shared__ float wsum[4];
    if ((tid & 63) == 0) wsum[tid >> 6] = v;
    __syncthreads();
    if (tid == 0)
        out[0] = (wsum[0] + wsum[1] + wsum[2] + wsum[3]) * (1.0f / (float)(B * N));
}

extern "C" void kernel_launch(void* const* d_in, const int* in_sizes, int n_in,
                              void* d_out, int out_size, void* d_ws, size_t ws_size,
                              hipStream_t stream) {
    const float* x = (const float*)d_in[0];
    const float* y = (const float*)d_in[1];
    float* out = (float*)d_out;
    float* ws  = (float*)d_ws;

    dim3 grid(N / TN, B);          // (32, 32) = 1024 blocks, exactly 4/CU
    euclid_loss_kernel<<<grid, 256, 0, stream>>>(x, y, ws);
    reduce_kernel<<<1, 256, 0, stream>>>(ws, out);
}

// Round 3
// 141.663 us; speedup vs baseline: 1.0689x; 1.0689x over previous
//
#include <hip/hip_runtime.h>

// EuclideanLoss: loss = (1/(B*N)) * sum_{b,n} w_n * sqrt(sum_d (x[b,n,d]-y[b,d,n])^2)
// w_n = 1.5 for n in {1,2}. B=32, N=8192, D=64, fp32. 134 MB moved, zero reuse.
//
// R8: R6 post-mortem — 48.6us, VALUBusy 2%, FETCH up to 101MB. Little's law says
// in-flight capacity is 10x+ what's needed at 25% occupancy, so the wall is a
// RATE: the scattered x pattern (64 distinct 128B lines per wave instr, line
// halves split across waves -> timing-dependent L1 refetch, long TA occupancy).
// Fix: remap so each x wave-instr touches 16 lines, 4 lanes/line, every line
// fully consumed by 2 adjacent instrs of the SAME wave (zero refetch, FETCH
// should drop back toward 67MB-x-side-ideal). y stays >=256B-contiguous
// segments. Pairing stays register-local: thread owns the SAME 4n x 8d on both
// sides. 2048 blocks (empirical best from R5-era sweep), 4KB LDS, no atomics.
//
// Mapping: wave w: nh=w>>1 (n-half of 64), dh=w&1 (d-half of 32).
//          lane g: c=g&15 (n-group of 4), dw=g>>4 (d-window of 8).
// Thread: n = n0+64nh+4c..+3, d = 32dh+8dw..+7.
//   x: 4 rows x 2 float4. Per instr: 16 rows x 4 offsets {0,32,64,96}B+16j
//      within the row's 128B half-line -> 16 lines/instr, fully covered by j=0,1.
//   y: 8 rows x 1 float4. Per instr: 4 rows x 256B contiguous segments.

constexpr int B  = 32;
constexpr int N  = 8192;
constexpr int D  = 64;
constexpr int TN = 128;               // n per block
constexpr int NBLK = (N / TN) * B;    // 2048 partials

__global__ __launch_bounds__(256) void euclid_loss_kernel(
    const float* __restrict__ x,   // [B, N, D]
    const float* __restrict__ y,   // [B, D, N]
    float* __restrict__ ws)        // [NBLK] per-block partials
{
    const int tid = threadIdx.x;
    const int w   = tid >> 6;
    const int g   = tid & 63;
    const int c   = g & 15;            // n-group within half
    const int dw  = g >> 4;            // d-window (0..3) of 8
    const int nh  = w >> 1;            // n-half (0..1)
    const int dh  = w & 1;             // d-half (0..1)
    const int n0  = blockIdx.x * TN;
    const int b   = blockIdx.y;
    const int nb  = n0 + nh * 64 + 4 * c;   // first of this thread's 4 n's
    const int d0  = dh * 32 + dw * 8;       // first of this thread's 8 d's

    const float* xp = x + ((size_t)b * N + nb) * D + d0;  // 4 rows, stride D
    const float* yp = y + ((size_t)b * D + d0) * N + nb;  // 8 rows, stride N

    float4 xr[4][2];
#pragma unroll
    for (int r = 0; r < 4; ++r) {
        xr[r][0] = *reinterpret_cast<const float4*>(xp + r * D + 0);
        xr[r][1] = *reinterpret_cast<const float4*>(xp + r * D + 4);
    }
    float4 yv[8];
#pragma unroll
    for (int jd = 0; jd < 8; ++jd)
        yv[jd] = *reinterpret_cast<const float4*>(yp + (size_t)jd * N);

    float acc[4] = {0.f, 0.f, 0.f, 0.f};
    // acc[r] over d = d0..d0+7: x component e of xr[r][j] pairs with yv[4j+e].comp(r)
#define ACC_R(r, CMP)                                          \
    { float t;                                                 \
      t = xr[r][0].x - yv[0].CMP; acc[r] += t * t;             \
      t = xr[r][0].y - yv[1].CMP; acc[r] += t * t;             \
      t = xr[r][0].z - yv[2].CMP; acc[r] += t * t;             \
      t = xr[r][0].w - yv[3].CMP; acc[r] += t * t;             \
      t = xr[r][1].x - yv[4].CMP; acc[r] += t * t;             \
      t = xr[r][1].y - yv[5].CMP; acc[r] += t * t;             \
      t = xr[r][1].z - yv[6].CMP; acc[r] += t * t;             \
      t = xr[r][1].w - yv[7].CMP; acc[r] += t * t; }
    ACC_R(0, x)
    ACC_R(1, y)
    ACC_R(2, z)
    ACC_R(3, w)
#undef ACC_R

    // Combine the 8 (dh,dw) partials per n via 4KB LDS.
    __shared__ float partF[2][4][128];   // [dh][dw][nh*64 + 4c + r]
    *reinterpret_cast<float4*>(&partF[dh][dw][nh * 64 + 4 * c]) =
        make_float4(acc[0], acc[1], acc[2], acc[3]);
    __syncthreads();

    float v = 0.f;
    if (tid < TN) {                      // finisher: one thread per n
        const int nh2 = tid >> 6;
        const int m   = tid & 63;
        float s = 0.f;
#pragma unroll
        for (int dh2 = 0; dh2 < 2; ++dh2)
#pragma unroll
            for (int dw2 = 0; dw2 < 4; ++dw2)
                s += partF[dh2][dw2][nh2 * 64 + m];
        const int n = n0 + tid;
        const float wt = (n == 1 || n == 2) ? 1.5f : 1.0f;
        v = wt * __builtin_sqrtf(s);
    }
#pragma unroll
    for (int off = 32; off > 0; off >>= 1) v += __shfl_down(v, off, 64);

    __shared__ float wsum[4];
    if ((tid & 63) == 0) wsum[tid >> 6] = v;
    __syncthreads();
    if (tid == 0)
        ws[blockIdx.y * gridDim.x + blockIdx.x] =
            wsum[0] + wsum[1] + wsum[2] + wsum[3];   // plain store, no atomic
}

__global__ __launch_bounds__(256) void reduce_kernel(
    const float* __restrict__ ws,  // [NBLK] = 2048
    float* __restrict__ out)       // [1]
{
    const int tid = threadIdx.x;
    float v = 0.f;
#pragma unroll
    for (int j = 0; j < NBLK / (256 * 4); ++j) {   // 2 float4 per thread
        const float4 p = *reinterpret_cast<const float4*>(ws + j * 1024 + tid * 4);
        v += p.x + p.y + p.z + p.w;
    }
#pragma unroll
    for (int off = 32; off > 0; off >>= 1) v += __shfl_down(v, off, 64);

    __shared__ float wsum[4];
    if ((tid & 63) == 0) wsum[tid >> 6] = v;
    __syncthreads();
    if (tid == 0)
        out[0] = (wsum[0] + wsum[1] + wsum[2] + wsum[3]) * (1.0f / (float)(B * N));
}

extern "C" void kernel_launch(void* const* d_in, const int* in_sizes, int n_in,
                              void* d_out, int out_size, void* d_ws, size_t ws_size,
                              hipStream_t stream) {
    const float* x = (const float*)d_in[0];
    const float* y = (const float*)d_in[1];
    float* out = (float*)d_out;
    float* ws  = (float*)d_ws;

    dim3 grid(N / TN, B);          // (64, 32) = 2048 blocks
    euclid_loss_kernel<<<grid, 256, 0, stream>>>(x, y, ws);
    reduce_kernel<<<1, 256, 0, stream>>>(ws, out);
}